// Round 1
// baseline (157.071 us; speedup 1.0000x reference)
//
#include <hip/hip_runtime.h>

#define N_NODES 100000
#define N_EDGES 3200000
#define N_SG    800000
#define RULES   9

// ---------------------------------------------------------------------------
// Kernel 1: per-edge fuzzy attention. One thread per edge.
// feat gather is random but the 1.6 MB table is L2-resident.
// ---------------------------------------------------------------------------
__global__ __launch_bounds__(256) void edge_attn_kernel(
    const float4* __restrict__ feat,   // N_NODES x 4, contiguous -> float4
    const int*    __restrict__ src,
    const int*    __restrict__ dst,
    const float*  __restrict__ M,      // 2 x 9  (row0 scales x1, row1 scales x2)
    const float*  __restrict__ B,      // 9
    float*        __restrict__ out)    // N_EDGES
{
    int e = blockIdx.x * blockDim.x + threadIdx.x;
    if (e >= N_EDGES) return;

    float4 fd = feat[dst[e]];
    float4 fs = feat[src[e]];
    float d0 = fd.x - fs.x, d1 = fd.y - fs.y;
    float v0 = fd.z - fs.z, v1 = fd.w - fs.w;

    float x1 = sqrtf(d0 * d0 + d1 * d1);
    float vn = sqrtf(v0 * v0 + v1 * v1);
    float cosv = (d0 * v0 + d1 * v1) / (x1 * vn + 1e-8f);
    cosv = fminf(fmaxf(cosv, -1.0f + 1e-6f), 1.0f - 1e-6f);
    float x2 = acosf(cosv) * 57.29577951308232f;   // degrees

    // gaussian memberships: m1 over x1 (means 0,2,4, sigma .75); m2 over x2
    // (means 0,90,180, sigma 30).  1/(2*.75^2)=0.8888889, 1/(2*30^2)=5.5555556e-4
    const float k1 = 0.888888888888889f;
    const float k2 = 5.555555555555556e-4f;
    float m1[3], m2[3];
    {
        float a;
        a = x1 - 0.0f;  m1[0] = __expf(-a * a * k1);
        a = x1 - 2.0f;  m1[1] = __expf(-a * a * k1);
        a = x1 - 4.0f;  m1[2] = __expf(-a * a * k1);
        a = x2 - 0.0f;   m2[0] = __expf(-a * a * k2);
        a = x2 - 90.0f;  m2[1] = __expf(-a * a * k2);
        a = x2 - 180.0f; m2[2] = __expf(-a * a * k2);
    }

    float num = 0.0f, den = 0.0f;
#pragma unroll
    for (int i = 0; i < 3; ++i) {
#pragma unroll
        for (int j = 0; j < 3; ++j) {
            int r = i * 3 + j;
            float t = fminf(m1[i], m2[j]);
            float c = fmaf(x1, M[r], fmaf(x2, M[RULES + r], B[r]));
            num = fmaf(t, c, num);
            den += t;
        }
    }
    out[e] = num / den;
}

// ---------------------------------------------------------------------------
// Kernel 2: sum of exp(out[idx[i]]) over the softmax subset.
// a is bounded (~[-1.1, 1.1]) so no max-subtraction is needed in f32.
// ---------------------------------------------------------------------------
__global__ __launch_bounds__(256) void softmax_sum_kernel(
    const int*   __restrict__ idx,
    const float* __restrict__ out,
    float*       __restrict__ acc)
{
    int i = blockIdx.x * blockDim.x + threadIdx.x;
    float v = 0.0f;
    if (i < N_SG) v = __expf(out[idx[i]]);

    // wave64 shuffle reduce
#pragma unroll
    for (int o = 32; o > 0; o >>= 1) v += __shfl_down(v, o, 64);

    __shared__ float wsum[4];
    if ((threadIdx.x & 63) == 0) wsum[threadIdx.x >> 6] = v;
    __syncthreads();
    if (threadIdx.x == 0) {
        float s = wsum[0] + wsum[1] + wsum[2] + wsum[3];
        atomicAdd(acc, s);   // device-scope by default
    }
}

// ---------------------------------------------------------------------------
// Kernel 3: finalize softmax rows.
// ---------------------------------------------------------------------------
__global__ __launch_bounds__(256) void softmax_write_kernel(
    const int*   __restrict__ idx,
    float*       __restrict__ out,
    const float* __restrict__ acc)
{
    int i = blockIdx.x * blockDim.x + threadIdx.x;
    if (i >= N_SG) return;
    float inv = 1.0f / acc[0];       // uniform scalar load
    int e = idx[i];
    out[e] = __expf(out[e]) * inv;
}

extern "C" void kernel_launch(void* const* d_in, const int* in_sizes, int n_in,
                              void* d_out, int out_size, void* d_ws, size_t ws_size,
                              hipStream_t stream)
{
    const float4* feat = (const float4*)d_in[0];
    const int*    src  = (const int*)d_in[1];
    const int*    dst  = (const int*)d_in[2];
    const int*    idx  = (const int*)d_in[3];   // edge_sg_ID, shape (1, N_SG)
    const float*  M    = (const float*)d_in[4]; // 2 x 9
    const float*  B    = (const float*)d_in[5]; // 9
    float* out = (float*)d_out;
    float* acc = (float*)d_ws;                  // 1 float accumulator

    // ws is poisoned to 0xAA before every timed launch — zero it on-stream.
    hipMemsetAsync(acc, 0, sizeof(float), stream);

    dim3 blk(256);
    dim3 gridA((N_EDGES + 255) / 256);
    dim3 gridS((N_SG + 255) / 256);

    edge_attn_kernel<<<gridA, blk, 0, stream>>>(feat, src, dst, M, B, out);
    softmax_sum_kernel<<<gridS, blk, 0, stream>>>(idx, out, acc);
    softmax_write_kernel<<<gridS, blk, 0, stream>>>(idx, out, acc);
}